// Round 4
// baseline (354.224 us; speedup 1.0000x reference)
//
#include <hip/hip_runtime.h>

#define NN 100000
#define NE 1200000
#define DIN 7
#define H 64
#define NG 64
#define NB_SCAN 98   // ceil(NN/1024)

#define NTEAM 8            // one team per XCD (blockIdx % 8 round-robin heuristic)
#define NODES_PER_TEAM 12500
#define BPT 128            // blocks per team

// ---- fp8 e4m3fn software codec (RNE encode, exact decode incl. denormals) ----
static __device__ __forceinline__ unsigned int f32_to_fp8(float f) {
    float af = fabsf(f);
    af = fminf(af, 448.0f);
    unsigned int s = (__float_as_uint(f) >> 24) & 0x80u;
    unsigned int u = __float_as_uint(af);
    unsigned int r = u + 0x0007FFFFu + ((u >> 20) & 1u);   // RNE into 3-bit mantissa
    unsigned int nrm = ((((r >> 23) & 0xFFu) - 120u) << 3) | ((r >> 20) & 7u);
    unsigned int den = (unsigned int)__float2int_rn(af * 512.0f);
    unsigned int mag = (af < 0.015625f) ? den : nrm;
    return s | mag;
}
static __device__ __forceinline__ float fp8_to_f32(unsigned int b) {
    unsigned int s = (b >> 7) & 1u, e = (b >> 3) & 15u, m = b & 7u;
    float nrm = __uint_as_float((s << 31) | ((e + 120u) << 23) | (m << 20));
    float den = __uint_as_float((s << 31) | 0x3B000000u) * (float)m;  // ±m × 2^-9
    return e ? nrm : den;
}

// ---------------- CSR build (XCD-team versions) ----------------
__global__ __launch_bounds__(256) void k_hist(const int* __restrict__ dst, int* __restrict__ cnt) {
    int team = blockIdx.x & 7;
    int blk  = blockIdx.x >> 3;
    int lo = team * NODES_PER_TEAM, hi = lo + NODES_PER_TEAM;
    for (int e = blk * 256 + threadIdx.x; e < NE; e += BPT * 256) {
        int d = dst[e];
        if (d >= lo && d < hi) atomicAdd(&cnt[d], 1);
    }
}

__global__ __launch_bounds__(256) void k_scan1(const int* __restrict__ cnt, int* __restrict__ partial) {
    int t = threadIdx.x, b = blockIdx.x;
    int base = b * 1024 + t * 4;
    int s = 0;
#pragma unroll
    for (int j = 0; j < 4; j++) { int i = base + j; if (i < NN) s += cnt[i]; }
    __shared__ int sd[256];
    sd[t] = s; __syncthreads();
    for (int off = 128; off > 0; off >>= 1) { if (t < off) sd[t] += sd[t + off]; __syncthreads(); }
    if (t == 0) partial[b] = sd[0];
}

__global__ void k_scan2(int* partial) {
    if (threadIdx.x == 0 && blockIdx.x == 0) {
        int run = 0;
        for (int i = 0; i < NB_SCAN; i++) { int v = partial[i]; partial[i] = run; run += v; }
        partial[NB_SCAN] = run;
    }
}

// scan3 also emits dinv (has cnt in registers already)
__global__ __launch_bounds__(256) void k_scan3(const int* __restrict__ cnt, const int* __restrict__ partial,
                                               int* __restrict__ row_ptr, int* __restrict__ cursor,
                                               float* __restrict__ dinv) {
    int t = threadIdx.x, b = blockIdx.x;
    int base = b * 1024 + t * 4;
    int v[4], pre[4], s = 0;
#pragma unroll
    for (int j = 0; j < 4; j++) { int i = base + j; v[j] = (i < NN) ? cnt[i] : 0; pre[j] = s; s += v[j]; }
    __shared__ int sd[256];
    sd[t] = s; __syncthreads();
    for (int off = 1; off < 256; off <<= 1) {
        int y = (t >= off) ? sd[t - off] : 0;
        __syncthreads();
        sd[t] += y;
        __syncthreads();
    }
    int excl = sd[t] - s + partial[b];
#pragma unroll
    for (int j = 0; j < 4; j++) {
        int i = base + j;
        if (i < NN) {
            int val = excl + pre[j];
            row_ptr[i] = val; cursor[i] = val;
            dinv[i] = rsqrtf((float)(v[j] + 1));   // +1 self-loop
        }
    }
    if (b == 0 && t == 0) row_ptr[NN] = NE;
}

__global__ __launch_bounds__(256) void k_scatter(const int* __restrict__ src, const int* __restrict__ dst,
                                                 int* __restrict__ cursor, int* __restrict__ col) {
    int team = blockIdx.x & 7;
    int blk  = blockIdx.x >> 3;
    int lo = team * NODES_PER_TEAM, hi = lo + NODES_PER_TEAM;
    for (int e = blk * 256 + threadIdx.x; e < NE; e += BPT * 256) {
        int d = dst[e];
        if (d >= lo && d < hi) {
            int p = atomicAdd(&cursor[d], 1);
            col[p] = src[e];
        }
    }
}

// ---------------- input projection: h = relu(x @ W_in + b_in) ----------------
__global__ __launch_bounds__(256) void k_inproj(const float* __restrict__ x, const float* __restrict__ Win,
                                                const float* __restrict__ bin, float* __restrict__ h) {
    __shared__ float Ws[DIN * H];
    for (int j = threadIdx.x; j < DIN * H; j += 256) Ws[j] = Win[j];
    __syncthreads();
    int idx = blockIdx.x * 256 + threadIdx.x;   // grid sized exactly NN*H/256
    int r = idx >> 6, c = idx & 63;
    float acc = bin[c];
#pragma unroll
    for (int k = 0; k < DIN; k++) acc += x[r * DIN + k] * Ws[k * H + c];
    h[idx] = fmaxf(acc, 0.f);
}

// ---------------- hws = fp8((h @ W) * dinv[row]), 16 uints (64 B) per row ----------------
__global__ __launch_bounds__(256) void k_gemm_scale(const float* __restrict__ A, const float* __restrict__ W,
                                                    const float* __restrict__ dinv,
                                                    unsigned int* __restrict__ out) {
    __shared__ float As[16][68];   // [k][row], stride 68 avoids bank conflicts
    __shared__ float Ws[16][64];   // [k][col]
    int tid = threadIdx.x;
    int r0 = blockIdx.x * 64;
    int tr = tid >> 4, tc = tid & 15;
    float acc[4][4] = {};
    for (int k0 = 0; k0 < H; k0 += 16) {
        int row = tid >> 2;
        int kk4 = (tid & 3) * 4;
        int gr = r0 + row;
        float4 av = make_float4(0.f, 0.f, 0.f, 0.f);
        if (gr < NN) av = *(const float4*)(A + gr * H + k0 + kk4);
        As[kk4 + 0][row] = av.x; As[kk4 + 1][row] = av.y;
        As[kk4 + 2][row] = av.z; As[kk4 + 3][row] = av.w;
        int wk = tid >> 4, wc4 = (tid & 15) * 4;
        *(float4*)&Ws[wk][wc4] = *(const float4*)(W + (k0 + wk) * H + wc4);
        __syncthreads();
#pragma unroll
        for (int kk = 0; kk < 16; kk++) {
            float a0 = As[kk][tr * 4 + 0], a1 = As[kk][tr * 4 + 1];
            float a2 = As[kk][tr * 4 + 2], a3 = As[kk][tr * 4 + 3];
            float4 bv = *(const float4*)&Ws[kk][tc * 4];
            acc[0][0] += a0 * bv.x; acc[0][1] += a0 * bv.y; acc[0][2] += a0 * bv.z; acc[0][3] += a0 * bv.w;
            acc[1][0] += a1 * bv.x; acc[1][1] += a1 * bv.y; acc[1][2] += a1 * bv.z; acc[1][3] += a1 * bv.w;
            acc[2][0] += a2 * bv.x; acc[2][1] += a2 * bv.y; acc[2][2] += a2 * bv.z; acc[2][3] += a2 * bv.w;
            acc[3][0] += a3 * bv.x; acc[3][1] += a3 * bv.y; acc[3][2] += a3 * bv.z; acc[3][3] += a3 * bv.w;
        }
        __syncthreads();
    }
#pragma unroll
    for (int i = 0; i < 4; i++) {
        int gr = r0 + tr * 4 + i;
        if (gr < NN) {
            float s = dinv[gr];
            unsigned int o = f32_to_fp8(acc[i][0] * s)
                           | (f32_to_fp8(acc[i][1] * s) << 8)
                           | (f32_to_fp8(acc[i][2] * s) << 16)
                           | (f32_to_fp8(acc[i][3] * s) << 24);
            out[gr * 16 + tc] = o;
        }
    }
}

// ---------------- fused aggregate + bias + BN + relu + residual ----------------
// 16 lanes per node (4 features/lane), 4 nodes per wave, unroll-4 per node:
// up to 16 outstanding 64B gathers per wave (vs 4 before) — latency-bound fix.
__global__ __launch_bounds__(256) void k_agg(const unsigned int* __restrict__ hws8,
                                             const int* __restrict__ row_ptr,
                                             const int* __restrict__ col, const float* __restrict__ dinv,
                                             const float* __restrict__ cb, const float* __restrict__ gamma,
                                             const float* __restrict__ beta, const float* __restrict__ mean,
                                             const float* __restrict__ var, float* __restrict__ h, int layer) {
    int tid = threadIdx.x;
    int sub = tid & 15;
    int v = blockIdx.x * 16 + (tid >> 4);   // grid exact: NN/16 blocks

    unsigned int w = hws8[v * 16 + sub];    // self-loop row
    float a0 = fp8_to_f32(w & 255u);
    float a1 = fp8_to_f32((w >> 8) & 255u);
    float a2 = fp8_to_f32((w >> 16) & 255u);
    float a3 = fp8_to_f32(w >> 24);

    int s = row_ptr[v], e = row_ptr[v + 1];
    int i = s;
    for (; i + 4 <= e; i += 4) {
        int u0 = col[i], u1 = col[i + 1], u2 = col[i + 2], u3 = col[i + 3];
        unsigned int w0 = hws8[u0 * 16 + sub];
        unsigned int w1 = hws8[u1 * 16 + sub];
        unsigned int w2 = hws8[u2 * 16 + sub];
        unsigned int w3 = hws8[u3 * 16 + sub];
        a0 += fp8_to_f32(w0 & 255u) + fp8_to_f32(w1 & 255u) + fp8_to_f32(w2 & 255u) + fp8_to_f32(w3 & 255u);
        a1 += fp8_to_f32((w0 >> 8) & 255u) + fp8_to_f32((w1 >> 8) & 255u) + fp8_to_f32((w2 >> 8) & 255u) + fp8_to_f32((w3 >> 8) & 255u);
        a2 += fp8_to_f32((w0 >> 16) & 255u) + fp8_to_f32((w1 >> 16) & 255u) + fp8_to_f32((w2 >> 16) & 255u) + fp8_to_f32((w3 >> 16) & 255u);
        a3 += fp8_to_f32(w0 >> 24) + fp8_to_f32(w1 >> 24) + fp8_to_f32(w2 >> 24) + fp8_to_f32(w3 >> 24);
    }
    for (; i < e; ++i) {
        unsigned int wu = hws8[col[i] * 16 + sub];
        a0 += fp8_to_f32(wu & 255u);
        a1 += fp8_to_f32((wu >> 8) & 255u);
        a2 += fp8_to_f32((wu >> 16) & 255u);
        a3 += fp8_to_f32(wu >> 24);
    }

    float dv = dinv[v];
    int f0 = sub * 4;
    float4 cbv = *(const float4*)(cb + f0);
    float4 mnv = *(const float4*)(mean + f0);
    float4 vrv = *(const float4*)(var + f0);
    float4 gmv = *(const float4*)(gamma + f0);
    float4 btv = *(const float4*)(beta + f0);

    float r0 = (a0 * dv + cbv.x - mnv.x) * rsqrtf(vrv.x + 1e-5f) * gmv.x + btv.x;
    float r1 = (a1 * dv + cbv.y - mnv.y) * rsqrtf(vrv.y + 1e-5f) * gmv.y + btv.y;
    float r2 = (a2 * dv + cbv.z - mnv.z) * rsqrtf(vrv.z + 1e-5f) * gmv.z + btv.z;
    float r3 = (a3 * dv + cbv.w - mnv.w) * rsqrtf(vrv.w + 1e-5f) * gmv.w + btv.w;
    r0 = fmaxf(r0, 0.f); r1 = fmaxf(r1, 0.f); r2 = fmaxf(r2, 0.f); r3 = fmaxf(r3, 0.f);
    if (layer) {
        float4 hp = *(const float4*)(h + v * H + f0);
        r0 += hp.x; r1 += hp.y; r2 += hp.z; r3 += hp.w;
    }
    *(float4*)(h + v * H + f0) = make_float4(r0, r1, r2, r3);
}

// ---------------- mean pool (batch is sorted) ----------------
#define POOL_CHUNK 128
__global__ __launch_bounds__(64) void k_pool(const float* __restrict__ h, const int* __restrict__ batch,
                                             float* __restrict__ sums, float* __restrict__ cntg) {
    int lane = threadIdx.x;
    int start = blockIdx.x * POOL_CHUNK;
    int end = start + POOL_CHUNK; if (end > NN) end = NN;
    float acc = 0.f, c = 0.f;
    int curg = batch[start];
    for (int n = start; n < end; ++n) {
        int g = batch[n];
        if (g != curg) {             // wave-uniform branch
            atomicAdd(&sums[curg * H + lane], acc);
            if (lane == 0) atomicAdd(&cntg[curg], c);
            acc = 0.f; c = 0.f; curg = g;
        }
        acc += h[n * H + lane];
        c += 1.f;
    }
    atomicAdd(&sums[curg * H + lane], acc);
    if (lane == 0) atomicAdd(&cntg[curg], c);
}

// ---------------- final MLP on pooled features ----------------
__global__ __launch_bounds__(64) void k_mlp(const float* __restrict__ sums, const float* __restrict__ cntg,
                                            const float* __restrict__ W1, const float* __restrict__ b1,
                                            const float* __restrict__ W2, const float* __restrict__ b2,
                                            float* __restrict__ out) {
    int g = threadIdx.x;
    float inv = 1.f / fmaxf(cntg[g], 1.f);
    float pooled[H];
#pragma unroll
    for (int k = 0; k < H; k++) pooled[k] = sums[g * H + k] * inv;
    float o = b2[0];
#pragma unroll
    for (int j = 0; j < H / 2; j++) {
        float z = b1[j];
#pragma unroll
        for (int k = 0; k < H; k++) z += pooled[k] * W1[k * (H / 2) + j];
        o += fmaxf(z, 0.f) * W2[j];
    }
    out[g] = o;
}

extern "C" void kernel_launch(void* const* d_in, const int* in_sizes, int n_in,
                              void* d_out, int out_size, void* d_ws, size_t ws_size,
                              hipStream_t stream) {
    const float* x     = (const float*)d_in[0];
    const int*   ei    = (const int*)d_in[1];
    const int*   batch = (const int*)d_in[2];
    const float* Win   = (const float*)d_in[3];
    const float* bin   = (const float*)d_in[4];
    const float* convW = (const float*)d_in[5];
    const float* convb = (const float*)d_in[6];
    const float* gamma = (const float*)d_in[7];
    const float* beta  = (const float*)d_in[8];
    const float* mean  = (const float*)d_in[9];
    const float* var   = (const float*)d_in[10];
    const float* W1    = (const float*)d_in[11];
    const float* b1    = (const float*)d_in[12];
    const float* W2    = (const float*)d_in[13];
    const float* b2    = (const float*)d_in[14];
    float* out = (float*)d_out;

    char* p = (char*)d_ws;
    auto alloc = [&](size_t bytes) -> void* {
        void* r = (void*)p;
        p += (bytes + 255) & ~(size_t)255;
        return r;
    };
    float*          h       = (float*)alloc((size_t)NN * H * 4);
    unsigned int*   hws8    = (unsigned int*)alloc((size_t)NN * 16 * 4);   // fp8 rows, 64 B each
    float*          dinv    = (float*)alloc((size_t)NN * 4);
    int*            row_ptr = (int*)alloc((size_t)(NN + 1) * 4);
    int*            cursor  = (int*)alloc((size_t)NN * 4);
    int*            partial = (int*)alloc((size_t)(NB_SCAN + 1) * 4);
    int*            col     = (int*)alloc((size_t)NE * 4);
    // zero-initialized region (single memset spans cnt..cntg)
    int*            cnt     = (int*)alloc((size_t)NN * 4);
    float*          sums    = (float*)alloc((size_t)NG * H * 4);
    float*          cntg    = (float*)alloc((size_t)NG * 4);

    const int* src  = ei;
    const int* dstp = ei + NE;

    size_t zspan = (size_t)((char*)(cntg + NG) - (char*)cnt);
    hipMemsetAsync(cnt, 0, zspan, stream);

    k_hist<<<NTEAM * BPT, 256, 0, stream>>>(dstp, cnt);
    k_scan1<<<NB_SCAN, 256, 0, stream>>>(cnt, partial);
    k_scan2<<<1, 64, 0, stream>>>(partial);
    k_scan3<<<NB_SCAN, 256, 0, stream>>>(cnt, partial, row_ptr, cursor, dinv);
    k_scatter<<<NTEAM * BPT, 256, 0, stream>>>(src, dstp, cursor, col);

    k_inproj<<<(NN * H) / 256, 256, 0, stream>>>(x, Win, bin, h);

    for (int l = 0; l < 2; l++) {
        k_gemm_scale<<<(NN + 63) / 64, 256, 0, stream>>>(h, convW + l * H * H, dinv, hws8);
        k_agg<<<NN / 16, 256, 0, stream>>>(hws8, row_ptr, col, dinv,
                                           convb + l * H, gamma + l * H, beta + l * H,
                                           mean + l * H, var + l * H, h, l);
    }

    k_pool<<<(NN + POOL_CHUNK - 1) / POOL_CHUNK, 64, 0, stream>>>(h, batch, sums, cntg);
    k_mlp<<<1, 64, 0, stream>>>(sums, cntg, W1, b1, W2, b2, out);
}

// Round 5
// 284.337 us; speedup vs baseline: 1.2458x; 1.2458x over previous
//
#include <hip/hip_runtime.h>

#define NN 100000
#define NE 1200000
#define DIN 7
#define H 64
#define NG 64
#define NB_SCAN 98   // ceil(NN/1024)

#define NTEAM 8            // one team per XCD (blockIdx % 8 round-robin heuristic)
#define NODES_PER_TEAM 12500
#define BPT 128            // blocks per team

// bf16 helpers (RNE encode; decode = shift/mask only)
static __device__ __forceinline__ unsigned int f2bf(float f) {
    unsigned int u = __float_as_uint(f);
    return (u + 0x7fffu + ((u >> 16) & 1u)) >> 16;
}
static __device__ __forceinline__ float bf_lo(unsigned int w) { return __uint_as_float(w << 16); }
static __device__ __forceinline__ float bf_hi(unsigned int w) { return __uint_as_float(w & 0xffff0000u); }

// ---------------- CSR build (XCD-team versions) ----------------
__global__ __launch_bounds__(256) void k_hist(const int* __restrict__ dst, int* __restrict__ cnt) {
    int team = blockIdx.x & 7;
    int blk  = blockIdx.x >> 3;
    int lo = team * NODES_PER_TEAM, hi = lo + NODES_PER_TEAM;
    for (int e = blk * 256 + threadIdx.x; e < NE; e += BPT * 256) {
        int d = dst[e];
        if (d >= lo && d < hi) atomicAdd(&cnt[d], 1);
    }
}

__global__ __launch_bounds__(256) void k_scan1(const int* __restrict__ cnt, int* __restrict__ partial) {
    int t = threadIdx.x, b = blockIdx.x;
    int base = b * 1024 + t * 4;
    int s = 0;
#pragma unroll
    for (int j = 0; j < 4; j++) { int i = base + j; if (i < NN) s += cnt[i]; }
    __shared__ int sd[256];
    sd[t] = s; __syncthreads();
    for (int off = 128; off > 0; off >>= 1) { if (t < off) sd[t] += sd[t + off]; __syncthreads(); }
    if (t == 0) partial[b] = sd[0];
}

__global__ void k_scan2(int* partial) {
    if (threadIdx.x == 0 && blockIdx.x == 0) {
        int run = 0;
        for (int i = 0; i < NB_SCAN; i++) { int v = partial[i]; partial[i] = run; run += v; }
        partial[NB_SCAN] = run;
    }
}

// scan3 also emits dinv (has cnt in registers already)
__global__ __launch_bounds__(256) void k_scan3(const int* __restrict__ cnt, const int* __restrict__ partial,
                                               int* __restrict__ row_ptr, int* __restrict__ cursor,
                                               float* __restrict__ dinv) {
    int t = threadIdx.x, b = blockIdx.x;
    int base = b * 1024 + t * 4;
    int v[4], pre[4], s = 0;
#pragma unroll
    for (int j = 0; j < 4; j++) { int i = base + j; v[j] = (i < NN) ? cnt[i] : 0; pre[j] = s; s += v[j]; }
    __shared__ int sd[256];
    sd[t] = s; __syncthreads();
    for (int off = 1; off < 256; off <<= 1) {
        int y = (t >= off) ? sd[t - off] : 0;
        __syncthreads();
        sd[t] += y;
        __syncthreads();
    }
    int excl = sd[t] - s + partial[b];
#pragma unroll
    for (int j = 0; j < 4; j++) {
        int i = base + j;
        if (i < NN) {
            int val = excl + pre[j];
            row_ptr[i] = val; cursor[i] = val;
            dinv[i] = rsqrtf((float)(v[j] + 1));   // +1 self-loop
        }
    }
    if (b == 0 && t == 0) row_ptr[NN] = NE;
}

__global__ __launch_bounds__(256) void k_scatter(const int* __restrict__ src, const int* __restrict__ dst,
                                                 int* __restrict__ cursor, int* __restrict__ col) {
    int team = blockIdx.x & 7;
    int blk  = blockIdx.x >> 3;
    int lo = team * NODES_PER_TEAM, hi = lo + NODES_PER_TEAM;
    for (int e = blk * 256 + threadIdx.x; e < NE; e += BPT * 256) {
        int d = dst[e];
        if (d >= lo && d < hi) {
            int p = atomicAdd(&cursor[d], 1);
            col[p] = src[e];
        }
    }
}

// ---------------- fused: h_tile = relu(x@Win+bin); hws = bf16((h_tile@W0)*dinv) ----------------
__global__ __launch_bounds__(256) void k_gemm0_fused(const float* __restrict__ x,
                                                     const float* __restrict__ Win, const float* __restrict__ bin,
                                                     const float* __restrict__ W0, const float* __restrict__ dinv,
                                                     unsigned int* __restrict__ hwsw) {
    __shared__ float xs[64][8];
    __shared__ float wsin[DIN * 64];
    __shared__ float bs[64];
    __shared__ __align__(16) float As[64][68];   // h_tile transposed [k][row]
    __shared__ __align__(16) float Wc[64][64];
    int tid = threadIdx.x;
    int r0 = blockIdx.x * 64;

    for (int idx = tid; idx < 64 * DIN; idx += 256) {
        int r = idx / DIN, k = idx - r * DIN;
        int gr = r0 + r;
        xs[r][k] = (gr < NN) ? x[gr * DIN + k] : 0.f;
    }
    for (int idx = tid; idx < DIN * 64; idx += 256) wsin[idx] = Win[idx];
    if (tid < 64) bs[tid] = bin[tid];
    for (int idx = tid; idx < 64 * 64; idx += 256) Wc[idx >> 6][idx & 63] = W0[idx];
    __syncthreads();

    {   // h_tile: each thread computes 16 outputs for one row
        int r = tid >> 2, q = tid & 3;
        float xr[DIN];
#pragma unroll
        for (int k = 0; k < DIN; k++) xr[k] = xs[r][k];
#pragma unroll
        for (int cc = 0; cc < 16; cc++) {
            int c = q * 16 + cc;
            float a = bs[c];
#pragma unroll
            for (int k = 0; k < DIN; k++) a += xr[k] * wsin[k * 64 + c];
            As[c][r] = fmaxf(a, 0.f);
        }
    }
    __syncthreads();

    int tr = tid >> 4, tc = tid & 15;
    float acc[4][4] = {};
#pragma unroll 4
    for (int kk = 0; kk < 64; kk++) {
        float a0 = As[kk][tr * 4 + 0], a1 = As[kk][tr * 4 + 1];
        float a2 = As[kk][tr * 4 + 2], a3 = As[kk][tr * 4 + 3];
        float4 bv = *(const float4*)&Wc[kk][tc * 4];
        acc[0][0] += a0 * bv.x; acc[0][1] += a0 * bv.y; acc[0][2] += a0 * bv.z; acc[0][3] += a0 * bv.w;
        acc[1][0] += a1 * bv.x; acc[1][1] += a1 * bv.y; acc[1][2] += a1 * bv.z; acc[1][3] += a1 * bv.w;
        acc[2][0] += a2 * bv.x; acc[2][1] += a2 * bv.y; acc[2][2] += a2 * bv.z; acc[2][3] += a2 * bv.w;
        acc[3][0] += a3 * bv.x; acc[3][1] += a3 * bv.y; acc[3][2] += a3 * bv.z; acc[3][3] += a3 * bv.w;
    }
#pragma unroll
    for (int i = 0; i < 4; i++) {
        int gr = r0 + tr * 4 + i;
        if (gr < NN) {
            float s = dinv[gr];
            uint2 o;
            o.x = f2bf(acc[i][0] * s) | (f2bf(acc[i][1] * s) << 16);
            o.y = f2bf(acc[i][2] * s) | (f2bf(acc[i][3] * s) << 16);
            *(uint2*)(hwsw + gr * 32 + tc * 2) = o;
        }
    }
}

// ---------------- layer-1 gemm: hws = bf16((h @ W1) * dinv) ----------------
__global__ __launch_bounds__(256) void k_gemm_scale(const float* __restrict__ A, const float* __restrict__ W,
                                                    const float* __restrict__ dinv,
                                                    unsigned int* __restrict__ hwsw) {
    __shared__ __align__(16) float As[16][68];
    __shared__ __align__(16) float Ws[16][64];
    int tid = threadIdx.x;
    int r0 = blockIdx.x * 64;
    int tr = tid >> 4, tc = tid & 15;
    float acc[4][4] = {};
    for (int k0 = 0; k0 < H; k0 += 16) {
        int row = tid >> 2;
        int kk4 = (tid & 3) * 4;
        int gr = r0 + row;
        float4 av = make_float4(0.f, 0.f, 0.f, 0.f);
        if (gr < NN) av = *(const float4*)(A + gr * H + k0 + kk4);
        As[kk4 + 0][row] = av.x; As[kk4 + 1][row] = av.y;
        As[kk4 + 2][row] = av.z; As[kk4 + 3][row] = av.w;
        int wk = tid >> 4, wc4 = (tid & 15) * 4;
        *(float4*)&Ws[wk][wc4] = *(const float4*)(W + (k0 + wk) * H + wc4);
        __syncthreads();
#pragma unroll
        for (int kk = 0; kk < 16; kk++) {
            float a0 = As[kk][tr * 4 + 0], a1 = As[kk][tr * 4 + 1];
            float a2 = As[kk][tr * 4 + 2], a3 = As[kk][tr * 4 + 3];
            float4 bv = *(const float4*)&Ws[kk][tc * 4];
            acc[0][0] += a0 * bv.x; acc[0][1] += a0 * bv.y; acc[0][2] += a0 * bv.z; acc[0][3] += a0 * bv.w;
            acc[1][0] += a1 * bv.x; acc[1][1] += a1 * bv.y; acc[1][2] += a1 * bv.z; acc[1][3] += a1 * bv.w;
            acc[2][0] += a2 * bv.x; acc[2][1] += a2 * bv.y; acc[2][2] += a2 * bv.z; acc[2][3] += a2 * bv.w;
            acc[3][0] += a3 * bv.x; acc[3][1] += a3 * bv.y; acc[3][2] += a3 * bv.z; acc[3][3] += a3 * bv.w;
        }
        __syncthreads();
    }
#pragma unroll
    for (int i = 0; i < 4; i++) {
        int gr = r0 + tr * 4 + i;
        if (gr < NN) {
            float s = dinv[gr];
            uint2 o;
            o.x = f2bf(acc[i][0] * s) | (f2bf(acc[i][1] * s) << 16);
            o.y = f2bf(acc[i][2] * s) | (f2bf(acc[i][3] * s) << 16);
            *(uint2*)(hwsw + gr * 32 + tc * 2) = o;
        }
    }
}

// ---------------- fused aggregate + bias + BN + relu + residual ----------------
// bf16 rows (128B), 16 lanes/node × uint2 (4 features), 4 nodes/wave, unroll-4:
// 16 outstanding gathers/wave with ~2 VALU wave-ops per edge of decode.
__global__ __launch_bounds__(256) void k_agg(const unsigned int* __restrict__ hwsw,
                                             const int* __restrict__ row_ptr,
                                             const int* __restrict__ col, const float* __restrict__ dinv,
                                             const float* __restrict__ cb, const float* __restrict__ gamma,
                                             const float* __restrict__ beta, const float* __restrict__ mean,
                                             const float* __restrict__ var, float* __restrict__ h, int layer) {
    int tid = threadIdx.x;
    int sub = tid & 15;
    int v = blockIdx.x * 16 + (tid >> 4);   // grid exact: NN/16 blocks

    uint2 w = *(const uint2*)(hwsw + v * 32 + sub * 2);   // self-loop row
    float a0 = bf_lo(w.x), a1 = bf_hi(w.x);
    float a2 = bf_lo(w.y), a3 = bf_hi(w.y);

    int s = row_ptr[v], e = row_ptr[v + 1];
    int i = s;
    for (; i + 4 <= e; i += 4) {
        int u0 = col[i], u1 = col[i + 1], u2 = col[i + 2], u3 = col[i + 3];
        uint2 w0 = *(const uint2*)(hwsw + u0 * 32 + sub * 2);
        uint2 w1 = *(const uint2*)(hwsw + u1 * 32 + sub * 2);
        uint2 w2 = *(const uint2*)(hwsw + u2 * 32 + sub * 2);
        uint2 w3 = *(const uint2*)(hwsw + u3 * 32 + sub * 2);
        a0 += bf_lo(w0.x) + bf_lo(w1.x) + bf_lo(w2.x) + bf_lo(w3.x);
        a1 += bf_hi(w0.x) + bf_hi(w1.x) + bf_hi(w2.x) + bf_hi(w3.x);
        a2 += bf_lo(w0.y) + bf_lo(w1.y) + bf_lo(w2.y) + bf_lo(w3.y);
        a3 += bf_hi(w0.y) + bf_hi(w1.y) + bf_hi(w2.y) + bf_hi(w3.y);
    }
    for (; i < e; ++i) {
        uint2 wu = *(const uint2*)(hwsw + col[i] * 32 + sub * 2);
        a0 += bf_lo(wu.x); a1 += bf_hi(wu.x);
        a2 += bf_lo(wu.y); a3 += bf_hi(wu.y);
    }

    float dv = dinv[v];
    int f0 = sub * 4;
    float4 cbv = *(const float4*)(cb + f0);
    float4 mnv = *(const float4*)(mean + f0);
    float4 vrv = *(const float4*)(var + f0);
    float4 gmv = *(const float4*)(gamma + f0);
    float4 btv = *(const float4*)(beta + f0);

    float r0 = (a0 * dv + cbv.x - mnv.x) * rsqrtf(vrv.x + 1e-5f) * gmv.x + btv.x;
    float r1 = (a1 * dv + cbv.y - mnv.y) * rsqrtf(vrv.y + 1e-5f) * gmv.y + btv.y;
    float r2 = (a2 * dv + cbv.z - mnv.z) * rsqrtf(vrv.z + 1e-5f) * gmv.z + btv.z;
    float r3 = (a3 * dv + cbv.w - mnv.w) * rsqrtf(vrv.w + 1e-5f) * gmv.w + btv.w;
    r0 = fmaxf(r0, 0.f); r1 = fmaxf(r1, 0.f); r2 = fmaxf(r2, 0.f); r3 = fmaxf(r3, 0.f);
    if (layer) {
        float4 hp = *(const float4*)(h + v * H + f0);
        r0 += hp.x; r1 += hp.y; r2 += hp.z; r3 += hp.w;
    }
    *(float4*)(h + v * H + f0) = make_float4(r0, r1, r2, r3);
}

// ---------------- mean pool (batch is sorted) ----------------
#define POOL_CHUNK 128
__global__ __launch_bounds__(64) void k_pool(const float* __restrict__ h, const int* __restrict__ batch,
                                             float* __restrict__ sums, float* __restrict__ cntg) {
    int lane = threadIdx.x;
    int start = blockIdx.x * POOL_CHUNK;
    int end = start + POOL_CHUNK; if (end > NN) end = NN;
    float acc = 0.f, c = 0.f;
    int curg = batch[start];
    for (int n = start; n < end; ++n) {
        int g = batch[n];
        if (g != curg) {             // wave-uniform branch
            atomicAdd(&sums[curg * H + lane], acc);
            if (lane == 0) atomicAdd(&cntg[curg], c);
            acc = 0.f; c = 0.f; curg = g;
        }
        acc += h[n * H + lane];
        c += 1.f;
    }
    atomicAdd(&sums[curg * H + lane], acc);
    if (lane == 0) atomicAdd(&cntg[curg], c);
}

// ---------------- final MLP on pooled features ----------------
__global__ __launch_bounds__(64) void k_mlp(const float* __restrict__ sums, const float* __restrict__ cntg,
                                            const float* __restrict__ W1, const float* __restrict__ b1,
                                            const float* __restrict__ W2, const float* __restrict__ b2,
                                            float* __restrict__ out) {
    int g = threadIdx.x;
    float inv = 1.f / fmaxf(cntg[g], 1.f);
    float pooled[H];
#pragma unroll
    for (int k = 0; k < H; k++) pooled[k] = sums[g * H + k] * inv;
    float o = b2[0];
#pragma unroll
    for (int j = 0; j < H / 2; j++) {
        float z = b1[j];
#pragma unroll
        for (int k = 0; k < H; k++) z += pooled[k] * W1[k * (H / 2) + j];
        o += fmaxf(z, 0.f) * W2[j];
    }
    out[g] = o;
}

extern "C" void kernel_launch(void* const* d_in, const int* in_sizes, int n_in,
                              void* d_out, int out_size, void* d_ws, size_t ws_size,
                              hipStream_t stream) {
    const float* x     = (const float*)d_in[0];
    const int*   ei    = (const int*)d_in[1];
    const int*   batch = (const int*)d_in[2];
    const float* Win   = (const float*)d_in[3];
    const float* bin   = (const float*)d_in[4];
    const float* convW = (const float*)d_in[5];
    const float* convb = (const float*)d_in[6];
    const float* gamma = (const float*)d_in[7];
    const float* beta  = (const float*)d_in[8];
    const float* mean  = (const float*)d_in[9];
    const float* var   = (const float*)d_in[10];
    const float* W1    = (const float*)d_in[11];
    const float* b1    = (const float*)d_in[12];
    const float* W2    = (const float*)d_in[13];
    const float* b2    = (const float*)d_in[14];
    float* out = (float*)d_out;

    char* p = (char*)d_ws;
    auto alloc = [&](size_t bytes) -> void* {
        void* r = (void*)p;
        p += (bytes + 255) & ~(size_t)255;
        return r;
    };
    float*          h       = (float*)alloc((size_t)NN * H * 4);
    unsigned int*   hwsw    = (unsigned int*)alloc((size_t)NN * 32 * 4);   // bf16 rows, 128 B each
    float*          dinv    = (float*)alloc((size_t)NN * 4);
    int*            row_ptr = (int*)alloc((size_t)(NN + 1) * 4);
    int*            cursor  = (int*)alloc((size_t)NN * 4);
    int*            partial = (int*)alloc((size_t)(NB_SCAN + 1) * 4);
    int*            col     = (int*)alloc((size_t)NE * 4);
    // zero-initialized region (single memset spans cnt..cntg)
    int*            cnt     = (int*)alloc((size_t)NN * 4);
    float*          sums    = (float*)alloc((size_t)NG * H * 4);
    float*          cntg    = (float*)alloc((size_t)NG * 4);

    const int* src  = ei;
    const int* dstp = ei + NE;

    size_t zspan = (size_t)((char*)(cntg + NG) - (char*)cnt);
    hipMemsetAsync(cnt, 0, zspan, stream);

    k_hist<<<NTEAM * BPT, 256, 0, stream>>>(dstp, cnt);
    k_scan1<<<NB_SCAN, 256, 0, stream>>>(cnt, partial);
    k_scan2<<<1, 64, 0, stream>>>(partial);
    k_scan3<<<NB_SCAN, 256, 0, stream>>>(cnt, partial, row_ptr, cursor, dinv);
    k_scatter<<<NTEAM * BPT, 256, 0, stream>>>(src, dstp, cursor, col);

    k_gemm0_fused<<<(NN + 63) / 64, 256, 0, stream>>>(x, Win, bin, convW, dinv, hwsw);
    k_agg<<<NN / 16, 256, 0, stream>>>(hwsw, row_ptr, col, dinv,
                                       convb, gamma, beta, mean, var, h, 0);
    k_gemm_scale<<<(NN + 63) / 64, 256, 0, stream>>>(h, convW + H * H, dinv, hwsw);
    k_agg<<<NN / 16, 256, 0, stream>>>(hwsw, row_ptr, col, dinv,
                                       convb + H, gamma + H, beta + H,
                                       mean + H, var + H, h, 1);

    k_pool<<<(NN + POOL_CHUNK - 1) / POOL_CHUNK, 64, 0, stream>>>(h, batch, sums, cntg);
    k_mlp<<<1, 64, 0, stream>>>(sums, cntg, W1, b1, W2, b2, out);
}